// Round 9
// baseline (32.079 us; speedup 1.0000x reference)
//
#include <hip/hip_runtime.h>
#include <stdint.h>

#define S_TOT 32768
#define MC_DIM 128
#define O_DIM 128
#define BN_EPS 1e-5f
#define S_TILE 64

// ws layout (float units):
#define WS_PART  0        // [512] pool partials: idx = half*256 + (b*128+c)
#define WS_BIAS  512      // [512] bias2[E=4][O=128]
#define WS_W2    1024     // 32768 float slots = W2 bf16 [E][O][MC] (65536 ushort)

typedef __attribute__((ext_vector_type(8))) short short8;
typedef __attribute__((ext_vector_type(4))) float f32x4;

static __device__ __forceinline__ unsigned short f2bf(float f) {
    union { float f; unsigned int u; } v; v.f = f;
    unsigned int r = v.u + 0x7FFFu + ((v.u >> 16) & 1u);
    return (unsigned short)(r >> 16);
}

// ---------------- K1: pool partials (shuffle reduce) + W2 fold  [verified r8] ----------------
__global__ __launch_bounds__(256) void k_pool(
    const float* __restrict__ f0, const float* __restrict__ f1,
    const float* __restrict__ f2, const float* __restrict__ f3,
    const float* __restrict__ Wc, const float* __restrict__ gamma,
    const float* __restrict__ beta, const float* __restrict__ rmean,
    const float* __restrict__ rvar, float* __restrict__ ws) {

    __shared__ float red[4];
    int bid = blockIdx.x;                    // 512 = half(2) x b(2) x c(128)
    int half = bid >> 8, ch = bid & 255;
    int b = ch >> 7, c = ch & 127;
    int t = threadIdx.x;
    int wv = t >> 6, l = t & 63;

    if (t < 32) {
        int i = bid * 32 + t;                // 16384 float4 quads total
        int eo = i >> 5;
        float inv = gamma[eo] * rsqrtf(rvar[eo] + BN_EPS);
        float4 w = ((const float4*)Wc)[i];
        uint2 pk;
        pk.x = (unsigned int)f2bf(w.x * inv) | ((unsigned int)f2bf(w.y * inv) << 16);
        pk.y = (unsigned int)f2bf(w.z * inv) | ((unsigned int)f2bf(w.w * inv) << 16);
        ((uint2*)(ws + WS_W2))[i] = pk;
    } else if (t == 32) {
        float inv = gamma[bid] * rsqrtf(rvar[bid] + BN_EPS);
        ws[WS_BIAS + bid] = beta[bid] - rmean[bid] * inv;
    }

    const float* fp = (c < 32) ? f0 : (c < 64) ? f1 : (c < 96) ? f2 : f3;
    const float4* base = (const float4*)(fp + ((size_t)b * 32 + (c & 31)) * S_TOT + half * 16384);
    float s = 0.f;
    #pragma unroll
    for (int j = 0; j < 16; ++j) {
        float4 v = base[j * 256 + t];
        s += (v.x + v.y) + (v.z + v.w);
    }
    #pragma unroll
    for (int msk = 32; msk >= 1; msk >>= 1) s += __shfl_xor(s, msk);
    if (l == 0) red[wv] = s;
    __syncthreads();
    if (t == 0) ws[WS_PART + half * 256 + ch] = (red[0] + red[1]) + (red[2] + red[3]);
}

// ---------------- K2: route + stage + dual-expert GEMM + BN/ReLU/combine (64-s tiles, 4 blk/CU) ----------------
__global__ __launch_bounds__(256, 4) void k_moe(
    const float* __restrict__ f0, const float* __restrict__ f1,
    const float* __restrict__ f2, const float* __restrict__ f3,
    const float* __restrict__ Wr, const float* __restrict__ br,
    const float* __restrict__ ws, float* __restrict__ out) {

    __shared__ uint4 tile4[1024];            // 16 KB swizzled xT tile: byte(s,c)=s*256+((c>>3)^(s&15))*16+(c&7)*2
    __shared__ float pooled[256];
    __shared__ int   route_e[2];
    __shared__ float route_w[2];
    char* lds = (char*)tile4;

    int bid = blockIdx.x;                    // 1024 = b(2) x st(512)
    int b = bid >> 9;
    int st = bid & 511;
    int s0 = st * S_TILE;
    int t = threadIdx.x;
    int wv = t >> 6, l = t & 63;

    // ---- stage x tile -> LDS (verified pattern; it-loop 2, cql = it*4+wv wave-uniform) ----
    #pragma unroll
    for (int m = 0; m < 4; ++m) {
        const float* fp = (m == 0) ? f0 : (m == 1) ? f1 : (m == 2) ? f2 : f3;
        #pragma unroll
        for (int it = 0; it < 2; ++it) {
            int lin = it * 256 + t;          // cql(8) x sl(64)
            int cql = lin >> 6;              // wave-uniform
            int sl = lin & 63;
            const float* src = fp + ((size_t)b * 32 + cql * 4) * S_TOT + s0 + sl;
            float v0 = src[0];
            float v1 = src[S_TOT];
            float v2 = src[2 * (size_t)S_TOT];
            float v3 = src[3 * (size_t)S_TOT];
            int cq = m * 8 + cql;            // global c-quad 0..31
            int gr = cq >> 1, half = cq & 1;
            int gswz = gr ^ (sl & 15);
            int byte = sl * 256 + gswz * 16 + half * 8;
            uint2 pk;
            pk.x = (unsigned int)f2bf(v0) | ((unsigned int)f2bf(v1) << 16);
            pk.y = (unsigned int)f2bf(v2) | ((unsigned int)f2bf(v3) << 16);
            *(uint2*)(lds + byte) = pk;
        }
    }

    // ---- redundant router (per block, verified) ----
    pooled[t] = ws[WS_PART + t] + ws[WS_PART + 256 + t];
    __syncthreads();
    if (t < 64) {
        const float s_inv = 1.0f / (float)S_TOT;
        float x0 = pooled[l] * s_inv;
        float x1 = pooled[64 + l] * s_inv;
        float y0 = pooled[128 + l] * s_inv;
        float y1 = pooled[192 + l] * s_inv;
        float lg[8];
        #pragma unroll
        for (int e = 0; e < 4; ++e) {
            float wc0 = Wr[e * MC_DIM + l];
            float wc1 = Wr[e * MC_DIM + 64 + l];
            lg[e] = x0 * wc0 + x1 * wc1;
            lg[4 + e] = y0 * wc0 + y1 * wc1;
        }
        #pragma unroll
        for (int msk = 32; msk >= 1; msk >>= 1) {
            #pragma unroll
            for (int e = 0; e < 8; ++e) lg[e] += __shfl_xor(lg[e], msk);
        }
        if (l == 0) {
            float probs[2][4];
            int top1[2];
            #pragma unroll
            for (int bb = 0; bb < 2; ++bb) {
                float lo[4];
                for (int e = 0; e < 4; ++e) lo[e] = lg[bb * 4 + e] + br[e];
                float mx = fmaxf(fmaxf(lo[0], lo[1]), fmaxf(lo[2], lo[3]));
                float sum = 0.f;
                for (int e = 0; e < 4; ++e) { probs[bb][e] = expf(lo[e] - mx); sum += probs[bb][e]; }
                for (int e = 0; e < 4; ++e) probs[bb][e] /= sum;
                int e0 = 0; float v0 = probs[bb][0];
                for (int e = 1; e < 4; ++e) if (probs[bb][e] > v0) { v0 = probs[bb][e]; e0 = e; }
                int e1 = -1; float v1 = -1.f;
                for (int e = 0; e < 4; ++e) if (e != e0 && probs[bb][e] > v1) { v1 = probs[bb][e]; e1 = e; }
                top1[bb] = e0;
                if (bb == b) {
                    float inv = 1.f / (v0 + v1);
                    route_e[0] = e0; route_e[1] = e1;
                    route_w[0] = v0 * inv; route_w[1] = v1 * inv;
                }
            }
            if (bid == 0) {
                float aux = 0.f;
                for (int e = 0; e < 4; ++e) {
                    float fe = 0.5f * ((top1[0] == e) + (top1[1] == e));
                    float pe = 0.5f * (probs[0][e] + probs[1][e]);
                    aux += fe * pe;
                }
                out[(size_t)8388608] = 4.f * aux;
            }
        }
    }
    __syncthreads();                          // staging LDS + route both ready

    int e0 = route_e[0], e1 = route_e[1];
    float w0 = route_w[0], w1 = route_w[1];
    const unsigned short* W2 = (const unsigned short*)(ws + WS_W2);
    const float* bias2 = ws + WS_BIAS;

    // ---- dual-expert MFMA GEMM (sf range 4) + bias + ReLU + combine ----
    int o0 = wv * 32;
    int lr = l & 15, lg2 = l >> 4;

    f32x4 acc[2][2][4];
    #pragma unroll
    for (int ee = 0; ee < 2; ++ee)
        #pragma unroll
        for (int of = 0; of < 2; ++of)
            #pragma unroll
            for (int sf = 0; sf < 4; ++sf)
                acc[ee][of][sf] = (f32x4){0.f, 0.f, 0.f, 0.f};

    #pragma unroll
    for (int kk = 0; kk < 4; ++kk) {
        short8 a[2][2];
        #pragma unroll
        for (int ee = 0; ee < 2; ++ee) {
            int e = ee ? e1 : e0;
            #pragma unroll
            for (int of = 0; of < 2; ++of) {
                int o = o0 + of * 16 + lr;   // A: row = lane&15
                a[ee][of] = *(const short8*)(W2 + ((size_t)(e * O_DIM + o) * MC_DIM + kk * 32 + lg2 * 8));
            }
        }
        #pragma unroll
        for (int sf = 0; sf < 4; ++sf) {
            int sl = sf * 16 + lr;           // B: col = lane&15
            int gr = kk * 4 + lg2;
            int byte = sl * 256 + ((gr ^ lr) << 4);
            short8 bb = *(const short8*)(lds + byte);
            #pragma unroll
            for (int ee = 0; ee < 2; ++ee)
                #pragma unroll
                for (int of = 0; of < 2; ++of)
                    acc[ee][of][sf] = __builtin_amdgcn_mfma_f32_16x16x32_bf16(
                        a[ee][of], bb, acc[ee][of][sf], 0, 0, 0);
        }
    }

    #pragma unroll
    for (int of = 0; of < 2; ++of) {
        #pragma unroll
        for (int r = 0; r < 4; ++r) {
            int o = o0 + of * 16 + lg2 * 4 + r;   // C/D: row = (lane>>4)*4 + reg
            float bA = bias2[e0 * O_DIM + o];
            float bB = bias2[e1 * O_DIM + o];
            float* orow = out + ((size_t)(b * O_DIM + o)) * S_TOT + s0;
            #pragma unroll
            for (int sf = 0; sf < 4; ++sf) {
                float y0 = fmaxf(acc[0][of][sf][r] + bA, 0.f);
                float y1 = fmaxf(acc[1][of][sf][r] + bB, 0.f);
                orow[sf * 16 + lr] = w0 * y0 + w1 * y1;
            }
        }
    }
}

extern "C" void kernel_launch(void* const* d_in, const int* in_sizes, int n_in,
                              void* d_out, int out_size, void* d_ws, size_t ws_size,
                              hipStream_t stream) {
    const float* f0    = (const float*)d_in[0];
    const float* f1    = (const float*)d_in[1];
    const float* f2    = (const float*)d_in[2];
    const float* f3    = (const float*)d_in[3];
    const float* Wc    = (const float*)d_in[4];
    const float* gamma = (const float*)d_in[5];
    const float* beta  = (const float*)d_in[6];
    const float* rmean = (const float*)d_in[7];
    const float* rvar  = (const float*)d_in[8];
    const float* Wr    = (const float*)d_in[9];
    const float* br    = (const float*)d_in[10];
    float* ws  = (float*)d_ws;
    float* out = (float*)d_out;

    hipLaunchKernelGGL(k_pool, dim3(512), dim3(256), 0, stream,
                       f0, f1, f2, f3, Wc, gamma, beta, rmean, rvar, ws);
    hipLaunchKernelGGL(k_moe, dim3(1024), dim3(256), 0, stream,
                       f0, f1, f2, f3, Wr, br, ws, out);
}

// Round 10
// 27.962 us; speedup vs baseline: 1.1472x; 1.1472x over previous
//
#include <hip/hip_runtime.h>
#include <stdint.h>

#define S_TOT 32768
#define MC_DIM 128
#define O_DIM 128
#define BN_EPS 1e-5f
#define S_TILE 128

// ws layout (float units):
#define WS_PART  0        // [256] pooled channel sums [b=2][c=128]
#define WS_BIAS  512      // [512] bias2[E=4][O=128]
#define WS_W2    1024     // 32768 float slots = W2 bf16 [E][O][MC] (65536 ushort)

typedef __attribute__((ext_vector_type(8))) short short8;
typedef __attribute__((ext_vector_type(4))) float f32x4;

static __device__ __forceinline__ unsigned short f2bf(float f) {
    union { float f; unsigned int u; } v; v.f = f;
    unsigned int r = v.u + 0x7FFFu + ((v.u >> 16) & 1u);
    return (unsigned short)(r >> 16);
}

// ---------------- K1: pooled sums (1 channel/block) + W2 fold ----------------
__global__ __launch_bounds__(256) void k_pool(
    const float* __restrict__ f0, const float* __restrict__ f1,
    const float* __restrict__ f2, const float* __restrict__ f3,
    const float* __restrict__ Wc, const float* __restrict__ gamma,
    const float* __restrict__ beta, const float* __restrict__ rmean,
    const float* __restrict__ rvar, float* __restrict__ ws) {

    __shared__ float red[4];
    int bid = blockIdx.x;                    // 256 = b(2) x c(128)
    int b = bid >> 7, c = bid & 127;
    int t = threadIdx.x;
    int wv = t >> 6, l = t & 63;

    // distributed W2 = bf16(Wc*inv): 16384 quads / 256 blocks = 64 each
    if (t < 64) {
        int i = bid * 64 + t;
        int eo = i >> 5;
        float inv = gamma[eo] * rsqrtf(rvar[eo] + BN_EPS);
        float4 w = ((const float4*)Wc)[i];
        uint2 pk;
        pk.x = (unsigned int)f2bf(w.x * inv) | ((unsigned int)f2bf(w.y * inv) << 16);
        pk.y = (unsigned int)f2bf(w.z * inv) | ((unsigned int)f2bf(w.w * inv) << 16);
        ((uint2*)(ws + WS_W2))[i] = pk;
    } else if (t < 66) {
        int i = bid * 2 + (t - 64);          // 512 bias entries / 256 blocks = 2 each
        float inv = gamma[i] * rsqrtf(rvar[i] + BN_EPS);
        ws[WS_BIAS + i] = beta[i] - rmean[i] * inv;
    }

    const float* fp = (c < 32) ? f0 : (c < 64) ? f1 : (c < 96) ? f2 : f3;
    const float4* base = (const float4*)(fp + ((size_t)b * 32 + (c & 31)) * S_TOT);
    float s = 0.f;
    #pragma unroll
    for (int j = 0; j < 32; ++j) {           // 256 thr * 32 * 4 = 32768 floats
        float4 v = base[j * 256 + t];
        s += (v.x + v.y) + (v.z + v.w);
    }
    #pragma unroll
    for (int msk = 32; msk >= 1; msk >>= 1) s += __shfl_xor(s, msk);
    if (l == 0) red[wv] = s;
    __syncthreads();
    if (t == 0) ws[WS_PART + bid] = (red[0] + red[1]) + (red[2] + red[3]);
}

// ---------------- K2: all-lane register router + stage + dual-expert GEMM ----------------
__global__ __launch_bounds__(256, 2) void k_moe(
    const float* __restrict__ f0, const float* __restrict__ f1,
    const float* __restrict__ f2, const float* __restrict__ f3,
    const float* __restrict__ Wr, const float* __restrict__ br,
    const float* __restrict__ ws, float* __restrict__ out) {

    __shared__ uint4 tile4[2048];            // 32 KB swizzled xT tile (verified layout)
    char* lds = (char*)tile4;

    int bid = blockIdx.x;                    // 512 = b(2) x st(256)
    int b = bid >> 8;
    int st = bid & 255;
    int s0 = st * S_TILE;
    int t = threadIdx.x;
    int wv = t >> 6, l = t & 63;

    // ---- all-lane register router (every wave redundant; no LDS, no sync, no serial lane) ----
    float lg[8];
    {
        float p0 = ws[WS_PART + l];          // pooled sums b=0
        float p1 = ws[WS_PART + 64 + l];
        float p2 = ws[WS_PART + 128 + l];    // b=1
        float p3 = ws[WS_PART + 192 + l];
        #pragma unroll
        for (int e = 0; e < 4; ++e) {
            float wc0 = Wr[e * MC_DIM + l];
            float wc1 = Wr[e * MC_DIM + 64 + l];
            lg[e]     = p0 * wc0 + p1 * wc1;
            lg[4 + e] = p2 * wc0 + p3 * wc1;
        }
        #pragma unroll
        for (int msk = 32; msk >= 1; msk >>= 1) {
            #pragma unroll
            for (int e = 0; e < 8; ++e) lg[e] += __shfl_xor(lg[e], msk);
        }
        // butterfly leaves full sums in EVERY lane
    }
    int e0, e1;
    float w0, w1;
    {
        const float s_inv = 1.0f / (float)S_TOT;
        float probs[2][4];
        int top1[2];
        int ee0[2], ee1[2];
        float vv0[2], vv1[2];
        #pragma unroll
        for (int bb = 0; bb < 2; ++bb) {
            float lo[4];
            #pragma unroll
            for (int e = 0; e < 4; ++e) lo[e] = lg[bb * 4 + e] * s_inv + br[e];
            float mx = fmaxf(fmaxf(lo[0], lo[1]), fmaxf(lo[2], lo[3]));
            float sum = 0.f;
            #pragma unroll
            for (int e = 0; e < 4; ++e) { probs[bb][e] = __expf(lo[e] - mx); sum += probs[bb][e]; }
            float rs = 1.f / sum;
            #pragma unroll
            for (int e = 0; e < 4; ++e) probs[bb][e] *= rs;
            int a0 = 0; float m0 = probs[bb][0];
            #pragma unroll
            for (int e = 1; e < 4; ++e) if (probs[bb][e] > m0) { m0 = probs[bb][e]; a0 = e; }
            int a1 = -1; float m1 = -1.f;
            #pragma unroll
            for (int e = 0; e < 4; ++e) if (e != a0 && probs[bb][e] > m1) { m1 = probs[bb][e]; a1 = e; }
            top1[bb] = a0; ee0[bb] = a0; ee1[bb] = a1; vv0[bb] = m0; vv1[bb] = m1;
        }
        float inv = 1.f / (vv0[b] + vv1[b]);
        e0 = ee0[b]; e1 = ee1[b];
        w0 = vv0[b] * inv; w1 = vv1[b] * inv;
        if (bid == 0 && t == 0) {
            float aux = 0.f;
            #pragma unroll
            for (int e = 0; e < 4; ++e) {
                float fe = 0.5f * ((top1[0] == e) + (top1[1] == e));
                float pe = 0.5f * (probs[0][e] + probs[1][e]);
                aux += fe * pe;
            }
            out[(size_t)8388608] = 4.f * aux;
        }
    }

    // ---- stage x tile -> LDS (r8-verified: coalesced dword loads, uint2 writes) ----
    // layout: byte(s, c) = s*256 + ((c>>3) ^ (s&15))*16 + (c&7)*2
    #pragma unroll
    for (int m = 0; m < 4; ++m) {
        const float* fp = (m == 0) ? f0 : (m == 1) ? f1 : (m == 2) ? f2 : f3;
        #pragma unroll
        for (int it = 0; it < 4; ++it) {
            int lin = it * 256 + t;          // cql(8) x sl(128)
            int cql = lin >> 7;              // wave-uniform
            int sl = lin & 127;
            const float* src = fp + ((size_t)b * 32 + cql * 4) * S_TOT + s0 + sl;
            float v0 = src[0];
            float v1 = src[S_TOT];
            float v2 = src[2 * (size_t)S_TOT];
            float v3 = src[3 * (size_t)S_TOT];
            int cq = m * 8 + cql;            // global c-quad 0..31
            int gr = cq >> 1, half = cq & 1;
            int gswz = gr ^ (sl & 15);
            int byte = sl * 256 + gswz * 16 + half * 8;
            uint2 pk;
            pk.x = (unsigned int)f2bf(v0) | ((unsigned int)f2bf(v1) << 16);
            pk.y = (unsigned int)f2bf(v2) | ((unsigned int)f2bf(v3) << 16);
            *(uint2*)(lds + byte) = pk;
        }
    }
    __syncthreads();                          // tile ready

    const unsigned short* W2 = (const unsigned short*)(ws + WS_W2);
    const float* bias2 = ws + WS_BIAS;

    // ---- dual-expert MFMA GEMM + bias + ReLU + combine (verified r8) ----
    int o0 = wv * 32;
    int lr = l & 15, lg2 = l >> 4;

    f32x4 acc[2][2][8];
    #pragma unroll
    for (int ee = 0; ee < 2; ++ee)
        #pragma unroll
        for (int of = 0; of < 2; ++of)
            #pragma unroll
            for (int sf = 0; sf < 8; ++sf)
                acc[ee][of][sf] = (f32x4){0.f, 0.f, 0.f, 0.f};

    #pragma unroll
    for (int kk = 0; kk < 4; ++kk) {
        short8 a[2][2];
        #pragma unroll
        for (int ee = 0; ee < 2; ++ee) {
            int e = ee ? e1 : e0;
            #pragma unroll
            for (int of = 0; of < 2; ++of) {
                int o = o0 + of * 16 + lr;   // A: row = lane&15
                a[ee][of] = *(const short8*)(W2 + ((size_t)(e * O_DIM + o) * MC_DIM + kk * 32 + lg2 * 8));
            }
        }
        #pragma unroll
        for (int sf = 0; sf < 8; ++sf) {
            int sl = sf * 16 + lr;           // B: col = lane&15
            int gr = kk * 4 + lg2;
            int byte = sl * 256 + ((gr ^ lr) << 4);
            short8 bb = *(const short8*)(lds + byte);
            #pragma unroll
            for (int ee = 0; ee < 2; ++ee)
                #pragma unroll
                for (int of = 0; of < 2; ++of)
                    acc[ee][of][sf] = __builtin_amdgcn_mfma_f32_16x16x32_bf16(
                        a[ee][of], bb, acc[ee][of][sf], 0, 0, 0);
        }
    }

    #pragma unroll
    for (int of = 0; of < 2; ++of) {
        #pragma unroll
        for (int r = 0; r < 4; ++r) {
            int o = o0 + of * 16 + lg2 * 4 + r;   // C/D: row = (lane>>4)*4 + reg
            float bA = bias2[e0 * O_DIM + o];
            float bB = bias2[e1 * O_DIM + o];
            float* orow = out + ((size_t)(b * O_DIM + o)) * S_TOT + s0;
            #pragma unroll
            for (int sf = 0; sf < 8; ++sf) {
                float y0 = fmaxf(acc[0][of][sf][r] + bA, 0.f);
                float y1 = fmaxf(acc[1][of][sf][r] + bB, 0.f);
                orow[sf * 16 + lr] = w0 * y0 + w1 * y1;
            }
        }
    }
}

extern "C" void kernel_launch(void* const* d_in, const int* in_sizes, int n_in,
                              void* d_out, int out_size, void* d_ws, size_t ws_size,
                              hipStream_t stream) {
    const float* f0    = (const float*)d_in[0];
    const float* f1    = (const float*)d_in[1];
    const float* f2    = (const float*)d_in[2];
    const float* f3    = (const float*)d_in[3];
    const float* Wc    = (const float*)d_in[4];
    const float* gamma = (const float*)d_in[5];
    const float* beta  = (const float*)d_in[6];
    const float* rmean = (const float*)d_in[7];
    const float* rvar  = (const float*)d_in[8];
    const float* Wr    = (const float*)d_in[9];
    const float* br    = (const float*)d_in[10];
    float* ws  = (float*)d_ws;
    float* out = (float*)d_out;

    hipLaunchKernelGGL(k_pool, dim3(256), dim3(256), 0, stream,
                       f0, f1, f2, f3, Wc, gamma, beta, rmean, rvar, ws);
    hipLaunchKernelGGL(k_moe, dim3(512), dim3(256), 0, stream,
                       f0, f1, f2, f3, Wr, br, ws, out);
}